// Round 4
// baseline (602.735 us; speedup 1.0000x reference)
//
#include <hip/hip_runtime.h>
#include <math.h>

#define T_LEN 256
#define BATCH 32
#define HID   768
#define GH    384   // 3*LSTM_H
#define LH    128   // LSTM_H
#define NLAB  9
#define M_TOT (T_LEN*BATCH)  // 8192

typedef float v2f __attribute__((ext_vector_type(2)));

// ---------------- K1: xp[t][b][0:768] = emb[ids] @ [Wih_f;Wih_b]^T + bias ----
__global__ __launch_bounds__(256) void k_gemm_xp(
    const int* __restrict__ ids, const float* __restrict__ emb,
    const float* __restrict__ Wf, const float* __restrict__ Wb,
    const float* __restrict__ bihf, const float* __restrict__ bihb,
    float* __restrict__ xp)
{
  __shared__ __align__(16) float As[8*128];
  __shared__ __align__(16) float Bs[8*128];
  const int tid = threadIdx.x;
  const int m0 = blockIdx.y * 128, n0 = blockIdx.x * 128;
  const int lrow = tid >> 1, c4 = (tid & 1) * 4;

  const int gm = m0 + lrow;
  const int tt = gm >> 5, bb = gm & 31;
  const int tok = ids[bb * T_LEN + tt];
  const float* aptr = emb + (size_t)tok * HID + c4;
  const int gn = n0 + lrow;
  const float* bptr = (gn < GH ? Wf + (size_t)gn * HID
                               : Wb + (size_t)(gn - GH) * HID) + c4;

  const int tx = tid & 15, ty = tid >> 4;
  float acc[8][8];
#pragma unroll
  for (int u = 0; u < 8; ++u)
#pragma unroll
    for (int v = 0; v < 8; ++v) acc[u][v] = 0.f;

  for (int k0 = 0; k0 < HID; k0 += 8) {
    float4 av = *reinterpret_cast<const float4*>(aptr + k0);
    float4 bv = *reinterpret_cast<const float4*>(bptr + k0);
    __syncthreads();
    As[(c4+0)*128 + lrow] = av.x;  As[(c4+1)*128 + lrow] = av.y;
    As[(c4+2)*128 + lrow] = av.z;  As[(c4+3)*128 + lrow] = av.w;
    Bs[(c4+0)*128 + lrow] = bv.x;  Bs[(c4+1)*128 + lrow] = bv.y;
    Bs[(c4+2)*128 + lrow] = bv.z;  Bs[(c4+3)*128 + lrow] = bv.w;
    __syncthreads();
#pragma unroll
    for (int kk = 0; kk < 8; ++kk) {
      float4 a0 = *reinterpret_cast<const float4*>(&As[kk*128 + ty*4]);
      float4 a1 = *reinterpret_cast<const float4*>(&As[kk*128 + 64 + ty*4]);
      float4 b0 = *reinterpret_cast<const float4*>(&Bs[kk*128 + tx*4]);
      float4 b1 = *reinterpret_cast<const float4*>(&Bs[kk*128 + 64 + tx*4]);
      float a[8] = {a0.x,a0.y,a0.z,a0.w,a1.x,a1.y,a1.z,a1.w};
      float b[8] = {b0.x,b0.y,b0.z,b0.w,b1.x,b1.y,b1.z,b1.w};
#pragma unroll
      for (int u = 0; u < 8; ++u)
#pragma unroll
        for (int v = 0; v < 8; ++v)
          acc[u][v] = fmaf(a[u], b[v], acc[u][v]);
    }
  }

  float bb8[8];
#pragma unroll
  for (int v = 0; v < 8; ++v) {
    int gc = n0 + tx*4 + (v & 3) + ((v >> 2) << 6);
    bb8[v] = (gc < GH) ? bihf[gc] : bihb[gc - GH];
  }
#pragma unroll
  for (int u = 0; u < 8; ++u) {
    int row = m0 + ty*4 + (u & 3) + ((u >> 2) << 6);
    float* orow = xp + (size_t)row * HID + n0;
    float4 o0, o1;
    o0.x = acc[u][0] + bb8[0]; o0.y = acc[u][1] + bb8[1];
    o0.z = acc[u][2] + bb8[2]; o0.w = acc[u][3] + bb8[3];
    o1.x = acc[u][4] + bb8[4]; o1.y = acc[u][5] + bb8[5];
    o1.z = acc[u][6] + bb8[6]; o1.w = acc[u][7] + bb8[7];
    *reinterpret_cast<float4*>(orow + tx*4)      = o0;
    *reinterpret_cast<float4*>(orow + 64 + tx*4) = o1;
  }
}

// DPP sum over 8 consecutive lanes (within a row of 16); result valid on the
// TOP lane of each 8-group (lane%8 == 7). row_shr pyramid, VALU pipe only.
__device__ __forceinline__ float dpp_sum8_hi(float x) {
  x += __int_as_float(__builtin_amdgcn_update_dpp(
        0, __float_as_int(x), 0x111, 0xf, 0xf, true));   // row_shr:1
  x += __int_as_float(__builtin_amdgcn_update_dpp(
        0, __float_as_int(x), 0x112, 0xf, 0xf, true));   // row_shr:2
  x += __int_as_float(__builtin_amdgcn_update_dpp(
        0, __float_as_int(x), 0x114, 0xf, 0xf, true));   // row_shr:4
  return x;
}

// ---------------- K2: bidirectional GRU recurrence (v4) ---------------------
// 64 blocks = (dir, batch); 512 threads = (unit-pair p = tid>>3, slice sl = tid&7).
// Thread computes 3 gates x 2 units over 16 k-values: w[3][2][8] v2f = 96 VGPRs.
// LDS h: 16-float slices padded to 20 -> 8 slice bases on disjoint bank groups,
// each address broadcast to 8 lanes: conflict-free. 4 ds_read_b128/thread/step
// (32 wave-instr, half of v3). Cross-slice reduce = 3 DPP adds (VALU pipe, no
// LDS). Sum lands on sl==7, which does activations for units 2p, 2p+1.
#define HIDX(j) (20*((j)>>4) + ((j)&15))
__global__ __launch_bounds__(512, 2) void k_gru(
    const float* __restrict__ xp,
    const float* __restrict__ Whhf, const float* __restrict__ Whhb,
    const float* __restrict__ bhhf, const float* __restrict__ bhhb,
    float* __restrict__ hbuf)
{
  __shared__ __align__(16) float hsp[2][160];
  const int tid = threadIdx.x;
  const int p   = tid >> 3;     // unit pair: units 2p, 2p+1
  const int sl  = tid & 7;      // k-slice: k in [16*sl, 16*sl+16)
  const int bd  = blockIdx.x;
  const int dir = bd >> 5, b = bd & 31;
  const float* Whh = dir ? Whhb : Whhf;
  const float* bhh = dir ? bhhb : bhhf;
  const int u0 = 2 * p;

  v2f w[3][2][8];
#pragma unroll
  for (int gate = 0; gate < 3; ++gate)
#pragma unroll
    for (int uu = 0; uu < 2; ++uu) {
      const float* wrow = Whh + (size_t)(gate * LH + u0 + uu) * LH + sl * 16;
#pragma unroll
      for (int j = 0; j < 4; ++j) {
        float4 w4 = *reinterpret_cast<const float4*>(wrow + j * 4);
        w[gate][uu][2*j]   = v2f{w4.x, w4.y};
        w[gate][uu][2*j+1] = v2f{w4.z, w4.w};
      }
    }
  const float br0 = bhh[u0],        br1 = bhh[u0+1];
  const float bz0 = bhh[u0+LH],     bz1 = bhh[u0+1+LH];
  const float bn0 = bhh[u0+2*LH],   bn1 = bhh[u0+1+2*LH];

  if (tid < 160) { hsp[0][tid] = 0.f; hsp[1][tid] = 0.f; }

  const int t0 = dir ? (T_LEN - 1) : 0;
  const int dt = dir ? -1 : 1;
  const float* xbase = xp + (size_t)b * HID + dir * GH + u0;
  float* hob = hbuf + (size_t)b * 256 + dir * LH + u0;

  float xr0=0.f,xz0=0.f,xn0=0.f,xr1=0.f,xz1=0.f,xn1=0.f;
  if (sl == 7) {
    const float* pp = xbase + (size_t)t0 * BATCH * HID;
    xr0 = pp[0]; xz0 = pp[LH]; xn0 = pp[2*LH];
    xr1 = pp[1]; xz1 = pp[1+LH]; xn1 = pp[1+2*LH];
  }
  float hp0 = 0.f, hp1 = 0.f;
  __syncthreads();

  int t = t0;
  for (int step = 0; step < T_LEN; ++step) {
    const int tn = (step < T_LEN - 1) ? (t + dt) : t;
    float xr0n=0.f,xz0n=0.f,xn0n=0.f,xr1n=0.f,xz1n=0.f,xn1n=0.f;
    if (sl == 7) {
      const float* pp = xbase + (size_t)tn * BATCH * HID;
      xr0n = pp[0]; xz0n = pp[LH]; xn0n = pp[2*LH];
      xr1n = pp[1]; xz1n = pp[1+LH]; xn1n = pp[1+2*LH];
    }

    const float* hc = &hsp[step & 1][20 * sl];
    float4 ha = *reinterpret_cast<const float4*>(hc);
    float4 hb = *reinterpret_cast<const float4*>(hc + 4);
    float4 hd = *reinterpret_cast<const float4*>(hc + 8);
    float4 he = *reinterpret_cast<const float4*>(hc + 12);
    v2f h[8] = { v2f{ha.x,ha.y}, v2f{ha.z,ha.w}, v2f{hb.x,hb.y}, v2f{hb.z,hb.w},
                 v2f{hd.x,hd.y}, v2f{hd.z,hd.w}, v2f{he.x,he.y}, v2f{he.z,he.w} };

    v2f a[3][2];
#pragma unroll
    for (int gate = 0; gate < 3; ++gate)
#pragma unroll
      for (int uu = 0; uu < 2; ++uu) {
        v2f s0 = v2f{0.f,0.f}, s1 = v2f{0.f,0.f};
#pragma unroll
        for (int j = 0; j < 8; j += 2) {
          s0 = __builtin_elementwise_fma(w[gate][uu][j],   h[j],   s0);
          s1 = __builtin_elementwise_fma(w[gate][uu][j+1], h[j+1], s1);
        }
        a[gate][uu] = s0 + s1;
      }
    float ar0 = dpp_sum8_hi(a[0][0].x + a[0][0].y);
    float ar1 = dpp_sum8_hi(a[0][1].x + a[0][1].y);
    float az0 = dpp_sum8_hi(a[1][0].x + a[1][0].y);
    float az1 = dpp_sum8_hi(a[1][1].x + a[1][1].y);
    float an0 = dpp_sum8_hi(a[2][0].x + a[2][0].y);
    float an1 = dpp_sum8_hi(a[2][1].x + a[2][1].y);

    if (sl == 7) {
      float r0 = __builtin_amdgcn_rcpf(1.f + __expf(-(xr0 + ar0 + br0)));
      float z0 = __builtin_amdgcn_rcpf(1.f + __expf(-(xz0 + az0 + bz0)));
      float e0 = __expf(2.f * (xn0 + r0 * (an0 + bn0)));
      float n0 = (e0 - 1.f) * __builtin_amdgcn_rcpf(e0 + 1.f);
      float h0 = (1.f - z0) * n0 + z0 * hp0;
      float r1 = __builtin_amdgcn_rcpf(1.f + __expf(-(xr1 + ar1 + br1)));
      float z1 = __builtin_amdgcn_rcpf(1.f + __expf(-(xz1 + az1 + bz1)));
      float e1 = __expf(2.f * (xn1 + r1 * (an1 + bn1)));
      float n1 = (e1 - 1.f) * __builtin_amdgcn_rcpf(e1 + 1.f);
      float h1 = (1.f - z1) * n1 + z1 * hp1;
      hp0 = h0; hp1 = h1;
      // u0 even, (u0&15)<=14 -> both in same padded slice, consecutive
      *reinterpret_cast<float2*>(&hsp[(step + 1) & 1][HIDX(u0)]) = float2{h0, h1};
      *reinterpret_cast<float2*>(hob + (size_t)t * BATCH * 256) = float2{h0, h1};
    }
    __syncthreads();
    xr0 = xr0n; xz0 = xz0n; xn0 = xn0n;
    xr1 = xr1n; xz1 = xz1n; xn1 = xn1n;
    t = tn;
  }
}

// ---------------- K3: emissions[b][t][9] = hbuf . Wlin^T + blin -------------
__global__ __launch_bounds__(256) void k_emis(
    const float* __restrict__ hbuf, const float* __restrict__ Wlin,
    const float* __restrict__ blin, float* __restrict__ e,
    float* __restrict__ lossp)
{
  if (blockIdx.x == 0 && threadIdx.x == 0) *lossp = 0.f;
  const int lane = threadIdx.x & 63, w = threadIdx.x >> 6;
  const int tokm = blockIdx.x * 4 + w;          // m = b*256 + t
  const int b = tokm >> 8, tt = tokm & 255;
  const float4 h4 = *reinterpret_cast<const float4*>(
      hbuf + ((size_t)tt * BATCH + b) * 256 + lane * 4);
  float acc[NLAB];
#pragma unroll
  for (int j = 0; j < NLAB; ++j) {
    const float4 w4 = *reinterpret_cast<const float4*>(Wlin + j * 256 + lane * 4);
    acc[j] = h4.x * w4.x + h4.y * w4.y + h4.z * w4.z + h4.w * w4.w;
  }
#pragma unroll
  for (int j = 0; j < NLAB; ++j)
#pragma unroll
    for (int off = 32; off > 0; off >>= 1)
      acc[j] += __shfl_xor(acc[j], off);
  if (lane == 0) {
#pragma unroll
    for (int j = 0; j < NLAB; ++j)
      e[(size_t)tokm * NLAB + j] = acc[j] + blin[j];
  }
}

// ---------------- K4: Viterbi (blocks 0..31) + CRF LLH (blocks 32..63) ------
__global__ __launch_bounds__(64) void k_crf(
    const float* __restrict__ e, const int* __restrict__ labels,
    const float* __restrict__ trans, const float* __restrict__ start,
    const float* __restrict__ endv, float* __restrict__ dec_out,
    float* __restrict__ lossp)
{
  __shared__ unsigned char bp8[(T_LEN-1) * 16];
  const int lane = threadIdx.x;
  const int bid  = blockIdx.x;
  const int b    = bid & 31;
  const float* eb = e + (size_t)b * T_LEN * NLAB;

  float tcol[NLAB];
#pragma unroll
  for (int i = 0; i < NLAB; ++i)
    tcol[i] = (lane < NLAB) ? trans[i * NLAB + lane] : 0.f;
  float alpha = (lane < NLAB) ? (start[lane] + eb[lane]) : -3e38f;

  if (bid < BATCH) {
    // ---- Viterbi ----
    for (int s = 0; s < T_LEN - 1; ++s) {
      float et = (lane < NLAB) ? eb[(s + 1) * NLAB + lane] : 0.f;
      float sv[NLAB];
#pragma unroll
      for (int i = 0; i < NLAB; ++i) sv[i] = __shfl(alpha, i);
      float best = sv[0] + tcol[0]; int bi = 0;
#pragma unroll
      for (int i = 1; i < NLAB; ++i) {
        float a = sv[i] + tcol[i];
        if (a > best) { best = a; bi = i; }   // strict >: first-max, matches jnp.argmax
      }
      alpha = best + et;
      if (lane < NLAB) bp8[s * 16 + lane] = (unsigned char)bi;
    }
    float fin = alpha + ((lane < NLAB) ? endv[lane] : 0.f);
    int last = 0; float bv = __shfl(fin, 0);
#pragma unroll
    for (int j = 1; j < NLAB; ++j) {
      float v = __shfl(fin, j);
      if (v > bv) { bv = v; last = j; }
    }
    if (lane == 0) {
      int y = last;
      dec_out[b * T_LEN + (T_LEN - 1)] = (float)y;
      uint4 row = *reinterpret_cast<const uint4*>(&bp8[(T_LEN - 2) * 16]);
      for (int s = T_LEN - 2; s >= 0; --s) {
        uint4 nrow = row;
        if (s > 0) nrow = *reinterpret_cast<const uint4*>(&bp8[(s - 1) * 16]);
        unsigned wsel = (y < 4) ? row.x : ((y < 8) ? row.y : row.z);
        y = (int)((wsel >> ((y & 3) * 8)) & 0xffu);
        dec_out[b * T_LEN + s] = (float)y;
        row = nrow;
      }
    }
  } else {
    // ---- CRF log-likelihood ----
    float ca = alpha;
    for (int s = 0; s < T_LEN - 1; ++s) {
      float et = (lane < NLAB) ? eb[(s + 1) * NLAB + lane] : 0.f;
      float c[NLAB];
#pragma unroll
      for (int i = 0; i < NLAB; ++i) c[i] = __shfl(ca, i) + tcol[i];
      float m = c[0];
#pragma unroll
      for (int i = 1; i < NLAB; ++i) m = fmaxf(m, c[i]);
      float p = 0.f;
#pragma unroll
      for (int i = 0; i < NLAB; ++i) p += expf(c[i] - m);
      ca = m + logf(p) + et;
    }
    float fv[NLAB]; float mx = -3e38f;
#pragma unroll
    for (int j = 0; j < NLAB; ++j) {
      fv[j] = __shfl(ca, j) + endv[j];
      mx = fmaxf(mx, fv[j]);
    }
    float ps = 0.f;
#pragma unroll
    for (int j = 0; j < NLAB; ++j) ps += expf(fv[j] - mx);
    float denom = mx + logf(ps);

    const int* lb = labels + b * T_LEN;
    float part = 0.f;
    for (int t4 = 0; t4 < 4; ++t4) {
      int t = lane * 4 + t4;
      int l = lb[t];
      part += eb[t * NLAB + l];
      if (t > 0) part += trans[lb[t - 1] * NLAB + l];
    }
#pragma unroll
    for (int off = 32; off > 0; off >>= 1) part += __shfl_xor(part, off);
    if (lane == 0) {
      float num = part + start[lb[0]] + endv[lb[T_LEN - 1]];
      float llh = num - denom;
      atomicAdd(lossp, -llh * (1.0f / BATCH));
    }
  }
}

extern "C" void kernel_launch(void* const* d_in, const int* in_sizes, int n_in,
                              void* d_out, int out_size, void* d_ws, size_t ws_size,
                              hipStream_t stream) {
  const int*   ids    = (const int*)d_in[0];
  const int*   labels = (const int*)d_in[2];
  const float* emb    = (const float*)d_in[3];
  const float* Wihf   = (const float*)d_in[4];
  const float* Whhf   = (const float*)d_in[5];
  const float* bihf   = (const float*)d_in[6];
  const float* bhhf   = (const float*)d_in[7];
  const float* Wihb   = (const float*)d_in[8];
  const float* Whhb   = (const float*)d_in[9];
  const float* bihb   = (const float*)d_in[10];
  const float* bhhb   = (const float*)d_in[11];
  const float* Wlin   = (const float*)d_in[12];
  const float* blin   = (const float*)d_in[13];
  const float* trans  = (const float*)d_in[14];
  const float* start  = (const float*)d_in[15];
  const float* endv   = (const float*)d_in[16];

  float* xp    = (float*)d_ws;                       // [T][B][768]
  float* hbuf  = xp + (size_t)M_TOT * HID;           // [T][B][256]
  float* e     = hbuf + (size_t)M_TOT * 256;         // [B][T][9]
  float* out   = (float*)d_out;                      // decoded as floats
  float* lossp = out + M_TOT;                        // loss scalar

  k_gemm_xp<<<dim3(6, 64), 256, 0, stream>>>(ids, emb, Wihf, Wihb, bihf, bihb, xp);
  k_gru<<<64, 512, 0, stream>>>(xp, Whhf, Whhb, bhhf, bhhb, hbuf);
  k_emis<<<M_TOT / 4, 256, 0, stream>>>(hbuf, Wlin, blin, e, lossp);
  k_crf<<<64, 64, 0, stream>>>(e, labels, trans, start, endv, out, lossp);
}

// Round 5
// 556.047 us; speedup vs baseline: 1.0840x; 1.0840x over previous
//
#include <hip/hip_runtime.h>
#include <math.h>

#define T_LEN 256
#define BATCH 32
#define HID   768
#define GH    384   // 3*LSTM_H
#define LH    128   // LSTM_H
#define NLAB  9
#define M_TOT (T_LEN*BATCH)  // 8192

typedef float v2f __attribute__((ext_vector_type(2)));

// ---------------- K1: xp[t][b][0:768] = emb[ids] @ [Wih_f;Wih_b]^T + bias ----
// 128x128 tile, BK=8, 256 threads, 8x8/thread. v2: register prefetch of the
// next k-tile issued between LDS store and barrier -> global latency hidden
// behind the 8-kk compute phase.
__global__ __launch_bounds__(256) void k_gemm_xp(
    const int* __restrict__ ids, const float* __restrict__ emb,
    const float* __restrict__ Wf, const float* __restrict__ Wb,
    const float* __restrict__ bihf, const float* __restrict__ bihb,
    float* __restrict__ xp)
{
  __shared__ __align__(16) float As[8*128];
  __shared__ __align__(16) float Bs[8*128];
  const int tid = threadIdx.x;
  const int m0 = blockIdx.y * 128, n0 = blockIdx.x * 128;
  const int lrow = tid >> 1, c4 = (tid & 1) * 4;

  const int gm = m0 + lrow;
  const int tt = gm >> 5, bb = gm & 31;
  const int tok = ids[bb * T_LEN + tt];
  const float* aptr = emb + (size_t)tok * HID + c4;
  const int gn = n0 + lrow;
  const float* bptr = (gn < GH ? Wf + (size_t)gn * HID
                               : Wb + (size_t)(gn - GH) * HID) + c4;

  const int tx = tid & 15, ty = tid >> 4;
  float acc[8][8];
#pragma unroll
  for (int u = 0; u < 8; ++u)
#pragma unroll
    for (int v = 0; v < 8; ++v) acc[u][v] = 0.f;

  float4 av = *reinterpret_cast<const float4*>(aptr);
  float4 bv = *reinterpret_cast<const float4*>(bptr);

  for (int k0 = 0; k0 < HID; k0 += 8) {
    __syncthreads();
    As[(c4+0)*128 + lrow] = av.x;  As[(c4+1)*128 + lrow] = av.y;
    As[(c4+2)*128 + lrow] = av.z;  As[(c4+3)*128 + lrow] = av.w;
    Bs[(c4+0)*128 + lrow] = bv.x;  Bs[(c4+1)*128 + lrow] = bv.y;
    Bs[(c4+2)*128 + lrow] = bv.z;  Bs[(c4+3)*128 + lrow] = bv.w;
    // prefetch next tile (latency hidden behind compute below)
    const int kn = (k0 + 8 < HID) ? (k0 + 8) : 0;
    float4 avn = *reinterpret_cast<const float4*>(aptr + kn);
    float4 bvn = *reinterpret_cast<const float4*>(bptr + kn);
    __syncthreads();
#pragma unroll
    for (int kk = 0; kk < 8; ++kk) {
      float4 a0 = *reinterpret_cast<const float4*>(&As[kk*128 + ty*4]);
      float4 a1 = *reinterpret_cast<const float4*>(&As[kk*128 + 64 + ty*4]);
      float4 b0 = *reinterpret_cast<const float4*>(&Bs[kk*128 + tx*4]);
      float4 b1 = *reinterpret_cast<const float4*>(&Bs[kk*128 + 64 + tx*4]);
      float a[8] = {a0.x,a0.y,a0.z,a0.w,a1.x,a1.y,a1.z,a1.w};
      float b[8] = {b0.x,b0.y,b0.z,b0.w,b1.x,b1.y,b1.z,b1.w};
#pragma unroll
      for (int u = 0; u < 8; ++u)
#pragma unroll
        for (int v = 0; v < 8; ++v)
          acc[u][v] = fmaf(a[u], b[v], acc[u][v]);
    }
    av = avn; bv = bvn;
  }

  float bb8[8];
#pragma unroll
  for (int v = 0; v < 8; ++v) {
    int gc = n0 + tx*4 + (v & 3) + ((v >> 2) << 6);
    bb8[v] = (gc < GH) ? bihf[gc] : bihb[gc - GH];
  }
#pragma unroll
  for (int u = 0; u < 8; ++u) {
    int row = m0 + ty*4 + (u & 3) + ((u >> 2) << 6);
    float* orow = xp + (size_t)row * HID + n0;
    float4 o0, o1;
    o0.x = acc[u][0] + bb8[0]; o0.y = acc[u][1] + bb8[1];
    o0.z = acc[u][2] + bb8[2]; o0.w = acc[u][3] + bb8[3];
    o1.x = acc[u][4] + bb8[4]; o1.y = acc[u][5] + bb8[5];
    o1.z = acc[u][6] + bb8[6]; o1.w = acc[u][7] + bb8[7];
    *reinterpret_cast<float4*>(orow + tx*4)      = o0;
    *reinterpret_cast<float4*>(orow + 64 + tx*4) = o1;
  }
}

// ---------------- K2: bidirectional GRU recurrence (v3 — reverted) ----------
// 64 blocks = (dir, batch); 512 threads = (unit g = tid>>2, K-quarter q = tid&3).
// v4's DPP reduction REGRESSED (latency chain, not LDS throughput, is binding)
// — keep v3: shfl_xor reduce, padded LDS h, double-buffer, one barrier/step.
__global__ __launch_bounds__(512, 2) void k_gru(
    const float* __restrict__ xp,
    const float* __restrict__ Whhf, const float* __restrict__ Whhb,
    const float* __restrict__ bhhf, const float* __restrict__ bhhb,
    float* __restrict__ hbuf)
{
  __shared__ __align__(16) float hsp[2][144];
  const int tid = threadIdx.x;
  const int g   = tid >> 2;     // hidden unit 0..127
  const int q   = tid & 3;      // K-quarter
  const int bd  = blockIdx.x;
  const int dir = bd >> 5, b = bd & 31;
  const float* Whh = dir ? Whhb : Whhf;
  const float* bhh = dir ? bhhb : bhhf;

  v2f w[3][16];
#pragma unroll
  for (int gate = 0; gate < 3; ++gate) {
    const float* wrow = Whh + (size_t)(gate * LH + g) * LH + q * 32;
#pragma unroll
    for (int j = 0; j < 8; ++j) {
      float4 w4 = *reinterpret_cast<const float4*>(wrow + j * 4);
      w[gate][2*j]   = v2f{w4.x, w4.y};
      w[gate][2*j+1] = v2f{w4.z, w4.w};
    }
  }
  const float br = bhh[g], bz = bhh[g + LH], bn = bhh[g + 2*LH];

  if (tid < LH) hsp[0][36*(tid >> 5) + (tid & 31)] = 0.f;

  const int t0   = dir ? (T_LEN - 1) : 0;
  const int dt   = dir ? -1 : 1;
  const float* xbase = xp + (size_t)b * HID + dir * GH + g;
  float* hob = hbuf + (size_t)b * 256 + dir * LH + g;

  float xr = 0.f, xz = 0.f, xn = 0.f;
  if (q == 0) {
    const float* p = xbase + (size_t)t0 * BATCH * HID;
    xr = p[0]; xz = p[LH]; xn = p[2*LH];
  }
  float hprev = 0.f;
  __syncthreads();

  int t = t0;
  for (int step = 0; step < T_LEN; ++step) {
    const int tn = (step < T_LEN - 1) ? (t + dt) : t;
    float xrn = 0.f, xzn = 0.f, xnn = 0.f;
    if (q == 0) {
      const float* p = xbase + (size_t)tn * BATCH * HID;
      xrn = p[0]; xzn = p[LH]; xnn = p[2*LH];
    }

    const float* hc = &hsp[step & 1][36 * q];
    v2f ar0 = v2f{0.f,0.f}, ar1 = ar0, az0 = ar0, az1 = ar0, an0 = ar0, an1 = ar0;
#pragma unroll
    for (int j = 0; j < 4; ++j) {
      float4 ha = *reinterpret_cast<const float4*>(hc + 8*j);
      float4 hb = *reinterpret_cast<const float4*>(hc + 8*j + 4);
      v2f h0 = v2f{ha.x, ha.y}, h1 = v2f{ha.z, ha.w};
      v2f h2 = v2f{hb.x, hb.y}, h3 = v2f{hb.z, hb.w};
      ar0 = __builtin_elementwise_fma(w[0][4*j+0], h0, ar0);
      ar1 = __builtin_elementwise_fma(w[0][4*j+1], h1, ar1);
      ar0 = __builtin_elementwise_fma(w[0][4*j+2], h2, ar0);
      ar1 = __builtin_elementwise_fma(w[0][4*j+3], h3, ar1);
      az0 = __builtin_elementwise_fma(w[1][4*j+0], h0, az0);
      az1 = __builtin_elementwise_fma(w[1][4*j+1], h1, az1);
      az0 = __builtin_elementwise_fma(w[1][4*j+2], h2, az0);
      az1 = __builtin_elementwise_fma(w[1][4*j+3], h3, az1);
      an0 = __builtin_elementwise_fma(w[2][4*j+0], h0, an0);
      an1 = __builtin_elementwise_fma(w[2][4*j+1], h1, an1);
      an0 = __builtin_elementwise_fma(w[2][4*j+2], h2, an0);
      an1 = __builtin_elementwise_fma(w[2][4*j+3], h3, an1);
    }
    float ar = (ar0.x + ar0.y) + (ar1.x + ar1.y);
    float az = (az0.x + az0.y) + (az1.x + az1.y);
    float an = (an0.x + an0.y) + (an1.x + an1.y);
    ar += __shfl_xor(ar, 1);  ar += __shfl_xor(ar, 2);
    az += __shfl_xor(az, 1);  az += __shfl_xor(az, 2);
    an += __shfl_xor(an, 1);  an += __shfl_xor(an, 2);

    if (q == 0) {
      float r  = __builtin_amdgcn_rcpf(1.f + __expf(-(xr + ar + br)));
      float z  = __builtin_amdgcn_rcpf(1.f + __expf(-(xz + az + bz)));
      float e2 = __expf(2.f * (xn + r * (an + bn)));
      float n  = (e2 - 1.f) * __builtin_amdgcn_rcpf(e2 + 1.f);
      float hnew = (1.f - z) * n + z * hprev;
      hprev = hnew;
      hsp[(step + 1) & 1][36*(g >> 5) + (g & 31)] = hnew;
      hob[(size_t)t * BATCH * 256] = hnew;
    }
    __syncthreads();
    xr = xrn; xz = xzn; xn = xnn;
    t = tn;
  }
}

// ---------------- K3: emissions[b][t][9] = hbuf . Wlin^T + blin -------------
__global__ __launch_bounds__(256) void k_emis(
    const float* __restrict__ hbuf, const float* __restrict__ Wlin,
    const float* __restrict__ blin, float* __restrict__ e,
    float* __restrict__ lossp)
{
  if (blockIdx.x == 0 && threadIdx.x == 0) *lossp = 0.f;
  const int lane = threadIdx.x & 63, w = threadIdx.x >> 6;
  const int tokm = blockIdx.x * 4 + w;          // m = b*256 + t
  const int b = tokm >> 8, tt = tokm & 255;
  const float4 h4 = *reinterpret_cast<const float4*>(
      hbuf + ((size_t)tt * BATCH + b) * 256 + lane * 4);
  float acc[NLAB];
#pragma unroll
  for (int j = 0; j < NLAB; ++j) {
    const float4 w4 = *reinterpret_cast<const float4*>(Wlin + j * 256 + lane * 4);
    acc[j] = h4.x * w4.x + h4.y * w4.y + h4.z * w4.z + h4.w * w4.w;
  }
#pragma unroll
  for (int j = 0; j < NLAB; ++j)
#pragma unroll
    for (int off = 32; off > 0; off >>= 1)
      acc[j] += __shfl_xor(acc[j], off);
  if (lane == 0) {
#pragma unroll
    for (int j = 0; j < NLAB; ++j)
      e[(size_t)tokm * NLAB + j] = acc[j] + blin[j];
  }
}

// ---------------- K4: Viterbi (blocks 0..31) + CRF LLH (blocks 32..63) ------
__global__ __launch_bounds__(64) void k_crf(
    const float* __restrict__ e, const int* __restrict__ labels,
    const float* __restrict__ trans, const float* __restrict__ start,
    const float* __restrict__ endv, float* __restrict__ dec_out,
    float* __restrict__ lossp)
{
  __shared__ unsigned char bp8[(T_LEN-1) * 16];
  const int lane = threadIdx.x;
  const int bid  = blockIdx.x;
  const int b    = bid & 31;
  const float* eb = e + (size_t)b * T_LEN * NLAB;

  float tcol[NLAB];
#pragma unroll
  for (int i = 0; i < NLAB; ++i)
    tcol[i] = (lane < NLAB) ? trans[i * NLAB + lane] : 0.f;
  float alpha = (lane < NLAB) ? (start[lane] + eb[lane]) : -3e38f;

  if (bid < BATCH) {
    // ---- Viterbi ----
    for (int s = 0; s < T_LEN - 1; ++s) {
      float et = (lane < NLAB) ? eb[(s + 1) * NLAB + lane] : 0.f;
      float sv[NLAB];
#pragma unroll
      for (int i = 0; i < NLAB; ++i) sv[i] = __shfl(alpha, i);
      float best = sv[0] + tcol[0]; int bi = 0;
#pragma unroll
      for (int i = 1; i < NLAB; ++i) {
        float a = sv[i] + tcol[i];
        if (a > best) { best = a; bi = i; }   // strict >: first-max, matches jnp.argmax
      }
      alpha = best + et;
      if (lane < NLAB) bp8[s * 16 + lane] = (unsigned char)bi;
    }
    float fin = alpha + ((lane < NLAB) ? endv[lane] : 0.f);
    int last = 0; float bv = __shfl(fin, 0);
#pragma unroll
    for (int j = 1; j < NLAB; ++j) {
      float v = __shfl(fin, j);
      if (v > bv) { bv = v; last = j; }
    }
    if (lane == 0) {
      int y = last;
      dec_out[b * T_LEN + (T_LEN - 1)] = (float)y;
      uint4 row = *reinterpret_cast<const uint4*>(&bp8[(T_LEN - 2) * 16]);
      for (int s = T_LEN - 2; s >= 0; --s) {
        uint4 nrow = row;
        if (s > 0) nrow = *reinterpret_cast<const uint4*>(&bp8[(s - 1) * 16]);
        unsigned wsel = (y < 4) ? row.x : ((y < 8) ? row.y : row.z);
        y = (int)((wsel >> ((y & 3) * 8)) & 0xffu);
        dec_out[b * T_LEN + s] = (float)y;
        row = nrow;
      }
    }
  } else {
    // ---- CRF log-likelihood ----
    float ca = alpha;
    for (int s = 0; s < T_LEN - 1; ++s) {
      float et = (lane < NLAB) ? eb[(s + 1) * NLAB + lane] : 0.f;
      float c[NLAB];
#pragma unroll
      for (int i = 0; i < NLAB; ++i) c[i] = __shfl(ca, i) + tcol[i];
      float m = c[0];
#pragma unroll
      for (int i = 1; i < NLAB; ++i) m = fmaxf(m, c[i]);
      float p = 0.f;
#pragma unroll
      for (int i = 0; i < NLAB; ++i) p += expf(c[i] - m);
      ca = m + logf(p) + et;
    }
    float fv[NLAB]; float mx = -3e38f;
#pragma unroll
    for (int j = 0; j < NLAB; ++j) {
      fv[j] = __shfl(ca, j) + endv[j];
      mx = fmaxf(mx, fv[j]);
    }
    float ps = 0.f;
#pragma unroll
    for (int j = 0; j < NLAB; ++j) ps += expf(fv[j] - mx);
    float denom = mx + logf(ps);

    const int* lb = labels + b * T_LEN;
    float part = 0.f;
    for (int t4 = 0; t4 < 4; ++t4) {
      int t = lane * 4 + t4;
      int l = lb[t];
      part += eb[t * NLAB + l];
      if (t > 0) part += trans[lb[t - 1] * NLAB + l];
    }
#pragma unroll
    for (int off = 32; off > 0; off >>= 1) part += __shfl_xor(part, off);
    if (lane == 0) {
      float num = part + start[lb[0]] + endv[lb[T_LEN - 1]];
      float llh = num - denom;
      atomicAdd(lossp, -llh * (1.0f / BATCH));
    }
  }
}

extern "C" void kernel_launch(void* const* d_in, const int* in_sizes, int n_in,
                              void* d_out, int out_size, void* d_ws, size_t ws_size,
                              hipStream_t stream) {
  const int*   ids    = (const int*)d_in[0];
  const int*   labels = (const int*)d_in[2];
  const float* emb    = (const float*)d_in[3];
  const float* Wihf   = (const float*)d_in[4];
  const float* Whhf   = (const float*)d_in[5];
  const float* bihf   = (const float*)d_in[6];
  const float* bhhf   = (const float*)d_in[7];
  const float* Wihb   = (const float*)d_in[8];
  const float* Whhb   = (const float*)d_in[9];
  const float* bihb   = (const float*)d_in[10];
  const float* bhhb   = (const float*)d_in[11];
  const float* Wlin   = (const float*)d_in[12];
  const float* blin   = (const float*)d_in[13];
  const float* trans  = (const float*)d_in[14];
  const float* start  = (const float*)d_in[15];
  const float* endv   = (const float*)d_in[16];

  float* xp    = (float*)d_ws;                       // [T][B][768]
  float* hbuf  = xp + (size_t)M_TOT * HID;           // [T][B][256]
  float* e     = hbuf + (size_t)M_TOT * 256;         // [B][T][9]
  float* out   = (float*)d_out;                      // decoded as floats
  float* lossp = out + M_TOT;                        // loss scalar

  k_gemm_xp<<<dim3(6, 64), 256, 0, stream>>>(ids, emb, Wihf, Wihb, bihf, bihb, xp);
  k_gru<<<64, 512, 0, stream>>>(xp, Whhf, Whhb, bhhf, bhhb, hbuf);
  k_emis<<<M_TOT / 4, 256, 0, stream>>>(hbuf, Wlin, blin, e, lossp);
  k_crf<<<64, 64, 0, stream>>>(e, labels, trans, start, endv, out, lossp);
}

// Round 6
// 469.061 us; speedup vs baseline: 1.2850x; 1.1854x over previous
//
#include <hip/hip_runtime.h>
#include <math.h>

#define T_LEN 256
#define BATCH 32
#define HID   768
#define GH    384   // 3*LSTM_H
#define LH    128   // LSTM_H
#define NLAB  9
#define M_TOT (T_LEN*BATCH)  // 8192

typedef float v2f __attribute__((ext_vector_type(2)));
typedef _Float16 h8 __attribute__((ext_vector_type(8)));
typedef float f4 __attribute__((ext_vector_type(4)));

#define LO_SCALE 1024.f
#define LO_INV   (1.f/1024.f)

// ---------------- K1: xp = emb[ids] @ [Wih_f;Wih_b]^T + bias  (MFMA v3) -----
// 128x128 tile, K staged 32 at a time as f16 hi + scaled-lo in LDS.
// C = Ah*Bh + (Ah*Bl_s + Al_s*Bh) * 2^-10  -> ~fp32 accuracy on 16x16x32 f16
// MFMA. Row stride 40 halfs (80B) -> even bank spread for b128 frag reads.
__global__ __launch_bounds__(256, 2) void k_gemm_xp(
    const int* __restrict__ ids, const float* __restrict__ emb,
    const float* __restrict__ Wf, const float* __restrict__ Wb,
    const float* __restrict__ bihf, const float* __restrict__ bihb,
    float* __restrict__ xp)
{
  __shared__ __align__(16) _Float16 Ah[128*40];
  __shared__ __align__(16) _Float16 Al[128*40];
  __shared__ __align__(16) _Float16 Bh[128*40];
  __shared__ __align__(16) _Float16 Bl[128*40];

  const int tid  = threadIdx.x;
  const int lane = tid & 63, w = tid >> 6;
  const int m0 = blockIdx.y * 128, n0 = blockIdx.x * 128;

  // staging: thread stages 16 consecutive k of one row of A and one row of B
  const int srow = tid >> 1, sk = (tid & 1) * 16;
  const int gm = m0 + srow;
  const int tok = ids[(gm & 31) * T_LEN + (gm >> 5)];
  const float* aG = emb + (size_t)tok * HID + sk;
  const int gn = n0 + srow;
  const float* bG = (gn < GH ? Wf + (size_t)gn * HID
                             : Wb + (size_t)(gn - GH) * HID) + sk;

  const int fr = lane & 15, fq = lane >> 4;
  const int mrow = (w & 1) * 64;   // wave m-offset in tile
  const int ncol = (w >> 1) * 64;  // wave n-offset in tile

  f4 acc[4][4];   // hi*hi
  f4 acc2[4][4];  // hi*lo_s + lo_s*hi  (scaled by 1024)
#pragma unroll
  for (int i = 0; i < 4; ++i)
#pragma unroll
    for (int j = 0; j < 4; ++j) { acc[i][j] = f4{0,0,0,0}; acc2[i][j] = f4{0,0,0,0}; }

  for (int kt = 0; kt < HID / 32; ++kt) {
    __syncthreads();
    {
      const float* pa = aG + kt * 32;
      const float* pb = bG + kt * 32;
      float av[16], bv[16];
#pragma unroll
      for (int c = 0; c < 4; ++c) {
        float4 a4 = *reinterpret_cast<const float4*>(pa + 4 * c);
        float4 b4 = *reinterpret_cast<const float4*>(pb + 4 * c);
        av[4*c] = a4.x; av[4*c+1] = a4.y; av[4*c+2] = a4.z; av[4*c+3] = a4.w;
        bv[4*c] = b4.x; bv[4*c+1] = b4.y; bv[4*c+2] = b4.z; bv[4*c+3] = b4.w;
      }
      h8 ah0, ah1, al0, al1, bh0, bh1, bl0, bl1;
#pragma unroll
      for (int c = 0; c < 8; ++c) {
        _Float16 h = (_Float16)av[c];
        ah0[c] = h; al0[c] = (_Float16)((av[c] - (float)h) * LO_SCALE);
        _Float16 h2 = (_Float16)av[c+8];
        ah1[c] = h2; al1[c] = (_Float16)((av[c+8] - (float)h2) * LO_SCALE);
        _Float16 g = (_Float16)bv[c];
        bh0[c] = g; bl0[c] = (_Float16)((bv[c] - (float)g) * LO_SCALE);
        _Float16 g2 = (_Float16)bv[c+8];
        bh1[c] = g2; bl1[c] = (_Float16)((bv[c+8] - (float)g2) * LO_SCALE);
      }
      const int sb = srow * 40 + sk;
      *reinterpret_cast<h8*>(&Ah[sb])     = ah0;
      *reinterpret_cast<h8*>(&Ah[sb + 8]) = ah1;
      *reinterpret_cast<h8*>(&Al[sb])     = al0;
      *reinterpret_cast<h8*>(&Al[sb + 8]) = al1;
      *reinterpret_cast<h8*>(&Bh[sb])     = bh0;
      *reinterpret_cast<h8*>(&Bh[sb + 8]) = bh1;
      *reinterpret_cast<h8*>(&Bl[sb])     = bl0;
      *reinterpret_cast<h8*>(&Bl[sb + 8]) = bl1;
    }
    __syncthreads();

    h8 fah[4], fal[4], fbh[4], fbl[4];
#pragma unroll
    for (int i = 0; i < 4; ++i) {
      const int off = (mrow + i * 16 + fr) * 40 + fq * 8;
      fah[i] = *reinterpret_cast<const h8*>(&Ah[off]);
      fal[i] = *reinterpret_cast<const h8*>(&Al[off]);
    }
#pragma unroll
    for (int j = 0; j < 4; ++j) {
      const int off = (ncol + j * 16 + fr) * 40 + fq * 8;
      fbh[j] = *reinterpret_cast<const h8*>(&Bh[off]);
      fbl[j] = *reinterpret_cast<const h8*>(&Bl[off]);
    }
#pragma unroll
    for (int i = 0; i < 4; ++i)
#pragma unroll
      for (int j = 0; j < 4; ++j) {
        acc[i][j]  = __builtin_amdgcn_mfma_f32_16x16x32_f16(fah[i], fbh[j], acc[i][j],  0, 0, 0);
        acc2[i][j] = __builtin_amdgcn_mfma_f32_16x16x32_f16(fah[i], fbl[j], acc2[i][j], 0, 0, 0);
        acc2[i][j] = __builtin_amdgcn_mfma_f32_16x16x32_f16(fal[i], fbh[j], acc2[i][j], 0, 0, 0);
      }
  }

  float bcol[4];
#pragma unroll
  for (int j = 0; j < 4; ++j) {
    const int c = n0 + ncol + j * 16 + fr;
    bcol[j] = (c < GH) ? bihf[c] : bihb[c - GH];
  }
#pragma unroll
  for (int i = 0; i < 4; ++i)
#pragma unroll
    for (int j = 0; j < 4; ++j) {
      const int col = n0 + ncol + j * 16 + fr;
#pragma unroll
      for (int r = 0; r < 4; ++r) {
        const int row = m0 + mrow + i * 16 + fq * 4 + r;
        xp[(size_t)row * HID + col] = acc[i][j][r] + acc2[i][j][r] * LO_INV + bcol[j];
      }
    }
}

// ---------------- K2: bidirectional GRU recurrence (v3 — frozen) ------------
__global__ __launch_bounds__(512, 2) void k_gru(
    const float* __restrict__ xp,
    const float* __restrict__ Whhf, const float* __restrict__ Whhb,
    const float* __restrict__ bhhf, const float* __restrict__ bhhb,
    float* __restrict__ hbuf)
{
  __shared__ __align__(16) float hsp[2][144];
  const int tid = threadIdx.x;
  const int g   = tid >> 2;     // hidden unit 0..127
  const int q   = tid & 3;      // K-quarter
  const int bd  = blockIdx.x;
  const int dir = bd >> 5, b = bd & 31;
  const float* Whh = dir ? Whhb : Whhf;
  const float* bhh = dir ? bhhb : bhhf;

  v2f w[3][16];
#pragma unroll
  for (int gate = 0; gate < 3; ++gate) {
    const float* wrow = Whh + (size_t)(gate * LH + g) * LH + q * 32;
#pragma unroll
    for (int j = 0; j < 8; ++j) {
      float4 w4 = *reinterpret_cast<const float4*>(wrow + j * 4);
      w[gate][2*j]   = v2f{w4.x, w4.y};
      w[gate][2*j+1] = v2f{w4.z, w4.w};
    }
  }
  const float br = bhh[g], bz = bhh[g + LH], bn = bhh[g + 2*LH];

  if (tid < LH) hsp[0][36*(tid >> 5) + (tid & 31)] = 0.f;

  const int t0   = dir ? (T_LEN - 1) : 0;
  const int dt   = dir ? -1 : 1;
  const float* xbase = xp + (size_t)b * HID + dir * GH + g;
  float* hob = hbuf + (size_t)b * 256 + dir * LH + g;

  float xr = 0.f, xz = 0.f, xn = 0.f;
  if (q == 0) {
    const float* p = xbase + (size_t)t0 * BATCH * HID;
    xr = p[0]; xz = p[LH]; xn = p[2*LH];
  }
  float hprev = 0.f;
  __syncthreads();

  int t = t0;
  for (int step = 0; step < T_LEN; ++step) {
    const int tn = (step < T_LEN - 1) ? (t + dt) : t;
    float xrn = 0.f, xzn = 0.f, xnn = 0.f;
    if (q == 0) {
      const float* p = xbase + (size_t)tn * BATCH * HID;
      xrn = p[0]; xzn = p[LH]; xnn = p[2*LH];
    }

    const float* hc = &hsp[step & 1][36 * q];
    v2f ar0 = v2f{0.f,0.f}, ar1 = ar0, az0 = ar0, az1 = ar0, an0 = ar0, an1 = ar0;
#pragma unroll
    for (int j = 0; j < 4; ++j) {
      float4 ha = *reinterpret_cast<const float4*>(hc + 8*j);
      float4 hb = *reinterpret_cast<const float4*>(hc + 8*j + 4);
      v2f h0 = v2f{ha.x, ha.y}, h1 = v2f{ha.z, ha.w};
      v2f h2 = v2f{hb.x, hb.y}, h3 = v2f{hb.z, hb.w};
      ar0 = __builtin_elementwise_fma(w[0][4*j+0], h0, ar0);
      ar1 = __builtin_elementwise_fma(w[0][4*j+1], h1, ar1);
      ar0 = __builtin_elementwise_fma(w[0][4*j+2], h2, ar0);
      ar1 = __builtin_elementwise_fma(w[0][4*j+3], h3, ar1);
      az0 = __builtin_elementwise_fma(w[1][4*j+0], h0, az0);
      az1 = __builtin_elementwise_fma(w[1][4*j+1], h1, az1);
      az0 = __builtin_elementwise_fma(w[1][4*j+2], h2, az0);
      az1 = __builtin_elementwise_fma(w[1][4*j+3], h3, az1);
      an0 = __builtin_elementwise_fma(w[2][4*j+0], h0, an0);
      an1 = __builtin_elementwise_fma(w[2][4*j+1], h1, an1);
      an0 = __builtin_elementwise_fma(w[2][4*j+2], h2, an0);
      an1 = __builtin_elementwise_fma(w[2][4*j+3], h3, an1);
    }
    float ar = (ar0.x + ar0.y) + (ar1.x + ar1.y);
    float az = (az0.x + az0.y) + (az1.x + az1.y);
    float an = (an0.x + an0.y) + (an1.x + an1.y);
    ar += __shfl_xor(ar, 1);  ar += __shfl_xor(ar, 2);
    az += __shfl_xor(az, 1);  az += __shfl_xor(az, 2);
    an += __shfl_xor(an, 1);  an += __shfl_xor(an, 2);

    if (q == 0) {
      float r  = __builtin_amdgcn_rcpf(1.f + __expf(-(xr + ar + br)));
      float z  = __builtin_amdgcn_rcpf(1.f + __expf(-(xz + az + bz)));
      float e2 = __expf(2.f * (xn + r * (an + bn)));
      float n  = (e2 - 1.f) * __builtin_amdgcn_rcpf(e2 + 1.f);
      float hnew = (1.f - z) * n + z * hprev;
      hprev = hnew;
      hsp[(step + 1) & 1][36*(g >> 5) + (g & 31)] = hnew;
      hob[(size_t)t * BATCH * 256] = hnew;
    }
    __syncthreads();
    xr = xrn; xz = xzn; xn = xnn;
    t = tn;
  }
}

// ---------------- K3: emissions[b][t][9] = hbuf . Wlin^T + blin -------------
__global__ __launch_bounds__(256) void k_emis(
    const float* __restrict__ hbuf, const float* __restrict__ Wlin,
    const float* __restrict__ blin, float* __restrict__ e,
    float* __restrict__ lossp)
{
  if (blockIdx.x == 0 && threadIdx.x == 0) *lossp = 0.f;
  const int lane = threadIdx.x & 63, w = threadIdx.x >> 6;
  const int tokm = blockIdx.x * 4 + w;          // m = b*256 + t
  const int b = tokm >> 8, tt = tokm & 255;
  const float4 h4 = *reinterpret_cast<const float4*>(
      hbuf + ((size_t)tt * BATCH + b) * 256 + lane * 4);
  float acc[NLAB];
#pragma unroll
  for (int j = 0; j < NLAB; ++j) {
    const float4 w4 = *reinterpret_cast<const float4*>(Wlin + j * 256 + lane * 4);
    acc[j] = h4.x * w4.x + h4.y * w4.y + h4.z * w4.z + h4.w * w4.w;
  }
#pragma unroll
  for (int j = 0; j < NLAB; ++j)
#pragma unroll
    for (int off = 32; off > 0; off >>= 1)
      acc[j] += __shfl_xor(acc[j], off);
  if (lane == 0) {
#pragma unroll
    for (int j = 0; j < NLAB; ++j)
      e[(size_t)tokm * NLAB + j] = acc[j] + blin[j];
  }
}

// ---------------- K4: Viterbi (blocks 0..31) + CRF LLH (blocks 32..63) ------
// v2: next-step emission prefetched one iteration ahead (global-load latency
// off the carried chain); argmax/max as depth-4 trees (first-max preserved:
// left arg always lower index, kept on >=).
__global__ __launch_bounds__(64) void k_crf(
    const float* __restrict__ e, const int* __restrict__ labels,
    const float* __restrict__ trans, const float* __restrict__ start,
    const float* __restrict__ endv, float* __restrict__ dec_out,
    float* __restrict__ lossp)
{
  __shared__ unsigned char bp8[(T_LEN-1) * 16];
  const int lane = threadIdx.x;
  const int bid  = blockIdx.x;
  const int b    = bid & 31;
  const float* eb = e + (size_t)b * T_LEN * NLAB;

  float tcol[NLAB];
#pragma unroll
  for (int i = 0; i < NLAB; ++i)
    tcol[i] = (lane < NLAB) ? trans[i * NLAB + lane] : 0.f;
  float alpha = (lane < NLAB) ? (start[lane] + eb[lane]) : -3e38f;

  if (bid < BATCH) {
    // ---- Viterbi ----
    float et_next = (lane < NLAB) ? eb[NLAB + lane] : 0.f;
    for (int s = 0; s < T_LEN - 1; ++s) {
      const float et = et_next;
      if (s < T_LEN - 2)
        et_next = (lane < NLAB) ? eb[(s + 2) * NLAB + lane] : 0.f;
      float v[NLAB];
#pragma unroll
      for (int i = 0; i < NLAB; ++i) v[i] = __shfl(alpha, i) + tcol[i];
      // depth-4 first-max tree
      float v01 = (v[0] >= v[1]) ? v[0] : v[1];  int i01 = (v[0] >= v[1]) ? 0 : 1;
      float v23 = (v[2] >= v[3]) ? v[2] : v[3];  int i23 = (v[2] >= v[3]) ? 2 : 3;
      float v45 = (v[4] >= v[5]) ? v[4] : v[5];  int i45 = (v[4] >= v[5]) ? 4 : 5;
      float v67 = (v[6] >= v[7]) ? v[6] : v[7];  int i67 = (v[6] >= v[7]) ? 6 : 7;
      float va = (v01 >= v23) ? v01 : v23;       int ia = (v01 >= v23) ? i01 : i23;
      float vb = (v45 >= v67) ? v45 : v67;       int ib = (v45 >= v67) ? i45 : i67;
      float vc = (va >= vb) ? va : vb;           int ic = (va >= vb) ? ia : ib;
      float best = (vc >= v[8]) ? vc : v[8];     int bi = (vc >= v[8]) ? ic : 8;
      alpha = best + et;
      if (lane < NLAB) bp8[s * 16 + lane] = (unsigned char)bi;
    }
    float fin = alpha + ((lane < NLAB) ? endv[lane] : 0.f);
    float fv[NLAB];
#pragma unroll
    for (int j = 0; j < NLAB; ++j) fv[j] = __shfl(fin, j);
    float f01 = (fv[0] >= fv[1]) ? fv[0] : fv[1];  int j01 = (fv[0] >= fv[1]) ? 0 : 1;
    float f23 = (fv[2] >= fv[3]) ? fv[2] : fv[3];  int j23 = (fv[2] >= fv[3]) ? 2 : 3;
    float f45 = (fv[4] >= fv[5]) ? fv[4] : fv[5];  int j45 = (fv[4] >= fv[5]) ? 4 : 5;
    float f67 = (fv[6] >= fv[7]) ? fv[6] : fv[7];  int j67 = (fv[6] >= fv[7]) ? 6 : 7;
    float fa = (f01 >= f23) ? f01 : f23;           int ja = (f01 >= f23) ? j01 : j23;
    float fb = (f45 >= f67) ? f45 : f67;           int jb = (f45 >= f67) ? j45 : j67;
    float fc = (fa >= fb) ? fa : fb;               int jc = (fa >= fb) ? ja : jb;
    int last = (fc >= fv[8]) ? jc : 8;
    if (lane == 0) {
      int y = last;
      dec_out[b * T_LEN + (T_LEN - 1)] = (float)y;
      uint4 row = *reinterpret_cast<const uint4*>(&bp8[(T_LEN - 2) * 16]);
      for (int s = T_LEN - 2; s >= 0; --s) {
        uint4 nrow = row;
        if (s > 0) nrow = *reinterpret_cast<const uint4*>(&bp8[(s - 1) * 16]);
        unsigned wsel = (y < 4) ? row.x : ((y < 8) ? row.y : row.z);
        y = (int)((wsel >> ((y & 3) * 8)) & 0xffu);
        dec_out[b * T_LEN + s] = (float)y;
        row = nrow;
      }
    }
  } else {
    // ---- CRF log-likelihood ----
    float ca = alpha;
    float et_next = (lane < NLAB) ? eb[NLAB + lane] : 0.f;
    for (int s = 0; s < T_LEN - 1; ++s) {
      const float et = et_next;
      if (s < T_LEN - 2)
        et_next = (lane < NLAB) ? eb[(s + 2) * NLAB + lane] : 0.f;
      float c[NLAB];
#pragma unroll
      for (int i = 0; i < NLAB; ++i) c[i] = __shfl(ca, i) + tcol[i];
      float m01 = fmaxf(c[0], c[1]), m23 = fmaxf(c[2], c[3]);
      float m45 = fmaxf(c[4], c[5]), m67 = fmaxf(c[6], c[7]);
      float m = fmaxf(fmaxf(fmaxf(m01, m23), fmaxf(m45, m67)), c[8]);
      float p0 = expf(c[0]-m) + expf(c[1]-m), p1 = expf(c[2]-m) + expf(c[3]-m);
      float p2 = expf(c[4]-m) + expf(c[5]-m), p3 = expf(c[6]-m) + expf(c[7]-m);
      float p = ((p0 + p1) + (p2 + p3)) + expf(c[8]-m);
      ca = m + logf(p) + et;
    }
    float fv[NLAB]; float mx = -3e38f;
#pragma unroll
    for (int j = 0; j < NLAB; ++j) {
      fv[j] = __shfl(ca, j) + endv[j];
      mx = fmaxf(mx, fv[j]);
    }
    float ps = 0.f;
#pragma unroll
    for (int j = 0; j < NLAB; ++j) ps += expf(fv[j] - mx);
    float denom = mx + logf(ps);

    const int* lb = labels + b * T_LEN;
    float part = 0.f;
    for (int t4 = 0; t4 < 4; ++t4) {
      int t = lane * 4 + t4;
      int l = lb[t];
      part += eb[t * NLAB + l];
      if (t > 0) part += trans[lb[t - 1] * NLAB + l];
    }
#pragma unroll
    for (int off = 32; off > 0; off >>= 1) part += __shfl_xor(part, off);
    if (lane == 0) {
      float num = part + start[lb[0]] + endv[lb[T_LEN - 1]];
      float llh = num - denom;
      atomicAdd(lossp, -llh * (1.0f / BATCH));
    }
  }
}

extern "C" void kernel_launch(void* const* d_in, const int* in_sizes, int n_in,
                              void* d_out, int out_size, void* d_ws, size_t ws_size,
                              hipStream_t stream) {
  const int*   ids    = (const int*)d_in[0];
  const int*   labels = (const int*)d_in[2];
  const float* emb    = (const float*)d_in[3];
  const float* Wihf   = (const float*)d_in[4];
  const float* Whhf   = (const float*)d_in[5];
  const float* bihf   = (const float*)d_in[6];
  const float* bhhf   = (const float*)d_in[7];
  const float* Wihb   = (const float*)d_in[8];
  const float* Whhb   = (const float*)d_in[9];
  const float* bihb   = (const float*)d_in[10];
  const float* bhhb   = (const float*)d_in[11];
  const float* Wlin   = (const float*)d_in[12];
  const float* blin   = (const float*)d_in[13];
  const float* trans  = (const float*)d_in[14];
  const float* start  = (const float*)d_in[15];
  const float* endv   = (const float*)d_in[16];

  float* xp    = (float*)d_ws;                       // [T][B][768]
  float* hbuf  = xp + (size_t)M_TOT * HID;           // [T][B][256]
  float* e     = hbuf + (size_t)M_TOT * 256;         // [B][T][9]
  float* out   = (float*)d_out;                      // decoded as floats
  float* lossp = out + M_TOT;                        // loss scalar

  k_gemm_xp<<<dim3(6, 64), 256, 0, stream>>>(ids, emb, Wihf, Wihb, bihf, bihb, xp);
  k_gru<<<64, 512, 0, stream>>>(xp, Whhf, Whhb, bhhf, bhhb, hbuf);
  k_emis<<<M_TOT / 4, 256, 0, stream>>>(hbuf, Wlin, blin, e, lossp);
  k_crf<<<64, 64, 0, stream>>>(e, labels, trans, start, endv, out, lossp);
}